// Round 9
// baseline (190.796 us; speedup 1.0000x reference)
//
#include <hip/hip_runtime.h>

#define RESO 128

// ---------------------------------------------------------------------------
// Kernel 1: prefix scans (tiny). ws layout (9 x 128 floats):
//   [0..2]=layers(x,y,z)  [3..5]=a3  [6..8]=a6
// ---------------------------------------------------------------------------
__global__ __launch_bounds__(128) void scan_kernel(
    const float* __restrict__ xL, const float* __restrict__ yL,
    const float* __restrict__ zL, const float* __restrict__ off,
    float* __restrict__ ws)
{
    __shared__ float s_tmp[4];
    __shared__ float s_a3[RESO];

    const int tid  = threadIdx.x;
    const int lane = tid & 63;
    const int wave = tid >> 6;

    for (int ax = 0; ax < 3; ++ax) {
        const float* L = (ax == 0) ? xL : (ax == 1) ? yL : zL;
        const float li   = L[tid];
        const float lim1 = (tid > 0) ? L[tid - 1] : 0.f;

        float v = (tid == 0) ? 0.f : 2.f * lim1 + 2.f * li;
        #pragma unroll
        for (int o = 1; o < 64; o <<= 1) {
            float u = __shfl_up(v, o, 64);
            if (lane >= o) v += u;
        }
        if (lane == 63) s_tmp[wave] = v;
        __syncthreads();
        if (wave == 1) v += s_tmp[0];
        const float a3v = off[ax] + v;
        s_a3[tid] = a3v;
        __syncthreads();

        const float a3m1 = (tid > 0) ? s_a3[tid - 1] : 0.f;
        float w = (tid == 0) ? 0.f : 3.f * lim1 + li + 2.f * a3m1;
        #pragma unroll
        for (int o = 1; o < 64; o <<= 1) {
            float u = __shfl_up(w, o, 64);
            if (lane >= o) w += u;
        }
        if (lane == 63) s_tmp[2 + wave] = w;
        __syncthreads();
        if (wave == 1) w += s_tmp[2];

        ws[ax * RESO + tid]       = li;
        ws[(3 + ax) * RESO + tid] = a3v;
        ws[(6 + ax) * RESO + tid] = w;
        __syncthreads();
    }
}

// ---------------------------------------------------------------------------
// Kernel 2: fused main pass, software-pipelined grid-stride.
// Each thread handles `iters` points per list; iteration t+1's global loads
// (2 idx + 2x3 point floats) are issued BEFORE computing iteration t from
// registers (double-buffered in named scalars). This keeps ~8 VMEM ops in
// flight per wave -> latency hidden by counted vmcnt waits instead of
// vmcnt(0) serialization (the R6 VGPR=16 pathology).
// Tables in LDS: tabS (L,a3,a6,.) float4 for sdf, tabR (L,a3) float2 for
// render. rsq replaces sqrt+div.
// ---------------------------------------------------------------------------
__global__ __launch_bounds__(256) void fused_kernel(
    const float* __restrict__ renderPts, const int* __restrict__ renderIdx,
    const float* __restrict__ sdfPts,    const int* __restrict__ sdfIdx,
    const float* __restrict__ ws,        const float* __restrict__ off,
    float* __restrict__ sdfOut, float* __restrict__ nrmOut, int N, int iters)
{
    __shared__ float4 tabS[3][RESO];
    __shared__ float2 tabR[3][RESO];

    const int tid = threadIdx.x;
    if (tid < RESO) {
        #pragma unroll
        for (int ax = 0; ax < 3; ++ax) {
            const float L  = ws[ax * RESO + tid];
            const float a3 = ws[(3 + ax) * RESO + tid];
            const float a6 = ws[(6 + ax) * RESO + tid];
            tabS[ax][tid] = make_float4(L, a3, a6, 0.f);
            tabR[ax][tid] = make_float2(L, a3);
        }
    }
    __syncthreads();

    const float off3   = off[3];
    const int   stride = gridDim.x * blockDim.x;
    int t = blockIdx.x * blockDim.x + tid;

    // ---- prologue: issue iteration-0 loads ----
    int   sidA = 0, ridA = 0;
    float spxA = 0.f, spyA = 0.f, spzA = 0.f;
    float rpxA = 0.f, rpyA = 0.f, rpzA = 0.f;
    if (t < N) {
        sidA = sdfIdx[t];
        const float* sp = &sdfPts[3 * t];
        spxA = sp[0]; spyA = sp[1]; spzA = sp[2];
        ridA = renderIdx[t];
        const float* rp = &renderPts[3 * t];
        rpxA = rp[0]; rpyA = rp[1]; rpzA = rp[2];
    }

    for (int it = 0; it < iters; ++it) {
        const int tn = t + stride;
        const bool more = (it + 1 < iters) && (tn < N);

        // ---- issue next iteration's loads (independent of current compute) ----
        int   sidB = 0, ridB = 0;
        float spxB = 0.f, spyB = 0.f, spzB = 0.f;
        float rpxB = 0.f, rpyB = 0.f, rpzB = 0.f;
        if (more) {
            sidB = sdfIdx[tn];
            const float* sp = &sdfPts[3 * tn];
            spxB = sp[0]; spyB = sp[1]; spzB = sp[2];
            ridB = renderIdx[tn];
            const float* rp = &renderPts[3 * tn];
            rpxB = rp[0]; rpyB = rp[1]; rpzB = rp[2];
        }

        if (t < N) {
            // ---------------- sdf ----------------
            const float4 tx = tabS[0][sidA & 127];
            const float4 ty = tabS[1][(sidA >> 7) & 127];
            const float4 tz = tabS[2][(sidA >> 14) & 127];
            const float a0 = tx.x * spxA;
            const float a1 = ty.x * spyA;
            const float a2 = tz.x * spzA;
            const float a6 = off3 + tx.z + ty.z + tz.z;
            const float num = (a0 + tx.y) * spxA + (a1 + ty.y) * spyA
                            + (a2 + tz.y) * spzA + a6;
            const float dx = 2.f * a0 + tx.y;
            const float dy = 2.f * a1 + ty.y;
            const float dz = 2.f * a2 + tz.y;
            const float d2 = dx * dx + dy * dy + dz * dz;
            sdfOut[t] = num * __builtin_amdgcn_rsqf(d2) * (1.0f / (float)RESO);

            // ---------------- render ----------------
            const float2 ux = tabR[0][ridA & 127];
            const float2 uy = tabR[1][(ridA >> 7) & 127];
            const float2 uz = tabR[2][(ridA >> 14) & 127];
            const float x = 2.f * ux.x * rpxA + ux.y;
            const float y = 2.f * uy.x * rpyA + uy.y;
            const float z = 2.f * uz.x * rpzA + uz.y;
            const float n2 = x * x + y * y + z * z;
            const float inv = __builtin_amdgcn_rsqf(fmaxf(n2, 1e-24f));
            float* no = &nrmOut[3 * t];
            no[0] = x * inv; no[1] = y * inv; no[2] = z * inv;
        }

        // ---- rotate buffers ----
        sidA = sidB; ridA = ridB;
        spxA = spxB; spyA = spyB; spzA = spzB;
        rpxA = rpxB; rpyA = rpyB; rpzA = rpzB;
        t = tn;
    }
}

// ---------------------------------------------------------------------------
// Inputs (setup_inputs order):
//  0 renderPointList (N*3 f32)   1 renderIndexList (N i32)
//  2 sdfPointList    (N*3 f32)   3 sdfIndexList    (N i32)
//  4 xLayer (128 f32) 5 yLayer (128 f32) 6 zLayer (128 f32) 7 offset (4 f32)
// Output: sdfList (N f32) ++ normalList (N*3 f32)
// ---------------------------------------------------------------------------
extern "C" void kernel_launch(void* const* d_in, const int* in_sizes, int n_in,
                              void* d_out, int out_size, void* d_ws, size_t ws_size,
                              hipStream_t stream)
{
    const float* renderPts = (const float*)d_in[0];
    const int*   renderIdx = (const int*)d_in[1];
    const float* sdfPts    = (const float*)d_in[2];
    const int*   sdfIdx    = (const int*)d_in[3];
    const float* xL        = (const float*)d_in[4];
    const float* yL        = (const float*)d_in[5];
    const float* zL        = (const float*)d_in[6];
    const float* off       = (const float*)d_in[7];

    float* ws  = (float*)d_ws;
    float* out = (float*)d_out;
    const int N = in_sizes[1];

    scan_kernel<<<1, 128, 0, stream>>>(xL, yL, zL, off, ws);

    const int block = 256;
    const int grid  = 4096;                       // 16 blocks/CU over the run
    const int total_threads = grid * block;       // 1,048,576
    const int iters = (N + total_threads - 1) / total_threads;  // 4 @ N=4.19M

    fused_kernel<<<grid, block, 0, stream>>>(renderPts, renderIdx, sdfPts, sdfIdx,
                                             ws, off, out, out + N, N, iters);
}